// Round 8
// baseline (363.324 us; speedup 1.0000x reference)
//
#include <hip/hip_runtime.h>

#define NPTS   32768
#define NCODES 8192
#define DIM    256

#define DECAYF 0.99f
#define ONE_MINUS_DECAYF ((float)(1.0 - 0.99))
#define EPSF   1e-5f
#define KEPSF  ((float)(8192.0 * 1e-5))
#define MARGIN 0.05f

// workspace byte offsets
#define WS_PART  0                                     // fp64 [8192] loss partials
#define WS_A     (WS_PART + NPTS / 4 * 8)              // fp32 [NPTS]
#define WS_EN    (WS_A + NPTS * 4)                     // fp32 [NCODES]
#define WS_CNT   (WS_EN + NCODES * 4)                  // int  [NCODES]
#define WS_S     (WS_CNT + NCODES * 4)                 // fp32 [NCODES] smoothed
#define WS_IDX   (WS_S + NCODES * 4)                   // int  [NPTS]
#define WS_OFFS  (WS_IDX + NPTS * 4)                   // int  [NCODES]
#define WS_CUR   (WS_OFFS + NCODES * 4)                // int  [NCODES]
#define WS_PLIST (WS_CUR + NCODES * 4)                 // int  [NPTS]
#define WS_EMBT  (WS_PLIST + NPTS * 4)                 // (unused, kept for layout)
#define WS_GMIN  (WS_EMBT + (size_t)DIM * NCODES * 4)  // fp32 [NPTS][512]     64 MB
#define WS_AH    (WS_GMIN + (size_t)NPTS * 512 * 4)    // bf16 [NPTS][256]     16 MB
#define WS_BH    (WS_AH + (size_t)NPTS * DIM * 2)      // bf16 [NCODES][256]    4 MB

typedef __attribute__((ext_vector_type(8))) short short8;
typedef __attribute__((ext_vector_type(4))) float f32x4;

__device__ inline void gl_lds16(const void* g, void* l) {
    __builtin_amdgcn_global_load_lds(
        (const __attribute__((address_space(1))) void*)g,
        (__attribute__((address_space(3))) void*)l, 16, 0, 0);
}

__device__ inline unsigned short f2bf(float f) {  // RNE float->bf16
    unsigned u = __float_as_uint(f);
    return (unsigned short)((u + 0x7FFFu + ((u >> 16) & 1u)) >> 16);
}
__device__ inline unsigned f2ord(float f) {       // monotone float->uint
    unsigned u = __float_as_uint(f);
    return (u & 0x80000000u) ? ~u : (u | 0x80000000u);
}

// ---------------------------------------------------------------------------
// Fused prep: row squared-norm + fp32->bf16-hi copy for BOTH z and emb, plus
// cnt zeroing (one launch replaces 3). Block-uniform branch on blockIdx.
__device__ __forceinline__ void rownorm_split_row(
    const float* __restrict__ x, float* __restrict__ outn,
    unsigned short* __restrict__ dst, int w, int lane) {
    const float4 v = *(const float4*)(x + (size_t)w * DIM + 4 * lane);
    ushort4 h;
    h.x = f2bf(v.x); h.y = f2bf(v.y); h.z = f2bf(v.z); h.w = f2bf(v.w);
    *(ushort4*)(dst + (size_t)w * DIM + 4 * lane) = h;
    float q0 = v.x * v.x, q1 = v.y * v.y, q2 = v.z * v.z, q3 = v.w * v.w;
    double s = (double)q0 + (double)q1 + (double)q2 + (double)q3;
    #pragma unroll
    for (int off = 32; off > 0; off >>= 1) s += __shfl_down(s, off);
    if (lane == 0) outn[w] = (float)s;
}

__global__ __launch_bounds__(256) void k_prep(
    const float* __restrict__ z, const float* __restrict__ emb,
    float* __restrict__ wA, unsigned short* __restrict__ wAh,
    float* __restrict__ wEn, unsigned short* __restrict__ wBh,
    int* __restrict__ cnt) {
    const int b = blockIdx.x;
    const int lane = threadIdx.x & 63;
    if (b < NPTS / 4) {
        int w = (b * 256 + (int)threadIdx.x) >> 6;
        rownorm_split_row(z, wA, wAh, w, lane);
    } else {
        int b2 = b - NPTS / 4;
        if (b2 < 32) cnt[b2 * 256 + threadIdx.x] = 0;
        int w = (b2 * 256 + (int)threadIdx.x) >> 6;
        rownorm_split_row(emb, wEn, wBh, w, lane);
    }
}

// ---------------------------------------------------------------------------
// Phase 1: bf16-hi MFMA GEMM (M=32768, N=8192, K=256), fused epilogue writes
// per-16-code-group approx min distance (fp32) to gmin[NPTS][512].
// (128x128 tile, 4 waves, 32KB LDS -- measured ~152us/~900TF, at this
// structure's ceiling; deeper pipelines measured WORSE on this shape.)
// DIAGNOSTIC SPLIT: launched as 4 quarter-grids (mbOff = 0,64,128,192) so
// non-GEMM kernels >~40us surface in the rocprof top-5. A-row reuse is
// within one mb-tile's 64 nb-blocks -> same-launch, no locality change.
__global__ __launch_bounds__(256) void k_gemm_argmin(
    const unsigned short* __restrict__ Ah,    // [NPTS][256] bf16 bits
    const unsigned short* __restrict__ Bh,    // [NCODES][256] bf16 bits
    const float* __restrict__ en,
    float* __restrict__ gmin,                 // [NPTS][512]
    int mbOff) {
    __shared__ __align__(16) unsigned short SBUF[16384];  // 32 KB: A | B

    const int t = threadIdx.x;
    const int w = t >> 6, l = t & 63;
    const int quad = l >> 4, l15 = l & 15;
    const int wr = w >> 1, wc = w & 1;
    const int mb = mbOff + (blockIdx.x >> 6), nb = blockIdx.x & 63;
    const int mBase = mb * 128, nBase = nb * 128;

    // staging swizzle: slot s covers (row=s>>3, x=s&7, kchunk = x ^ (row&7))
    const int xr = (t & 7) ^ ((t >> 3) & 7);
    const int rrow = t >> 3;
    const unsigned short* ag[4];
    const unsigned short* bg[4];
    #pragma unroll
    for (int i = 0; i < 4; ++i) {
        ag[i] = Ah + (size_t)(mBase + i * 32 + rrow) * DIM + xr * 8;
        bg[i] = Bh + (size_t)(nBase + i * 32 + rrow) * DIM + xr * 8;
    }

    f32x4 acc[4][4];
    #pragma unroll
    for (int i = 0; i < 4; ++i)
        #pragma unroll
        for (int j = 0; j < 4; ++j)
            acc[i][j] = (f32x4){0.f, 0.f, 0.f, 0.f};

    for (int kt = 0; kt < 4; ++kt) {
        __syncthreads();
        #pragma unroll
        for (int i = 0; i < 4; ++i) {
            gl_lds16(ag[i], &SBUF[(i * 256 + w * 64) * 8]);
            gl_lds16(bg[i], &SBUF[8192 + (i * 256 + w * 64) * 8]);
            ag[i] += 64; bg[i] += 64;
        }
        __syncthreads();
        #pragma unroll
        for (int kk = 0; kk < 2; ++kk) {
            const int kc = kk * 4 + quad;
            short8 a[4], b[4];
            #pragma unroll
            for (int ti = 0; ti < 4; ++ti) {
                int m = wr * 64 + ti * 16 + l15;
                a[ti] = *(const short8*)&SBUF[(m * 8 + (kc ^ (m & 7))) * 8];
                int n = wc * 64 + ti * 16 + l15;
                b[ti] = *(const short8*)&SBUF[8192 + (n * 8 + (kc ^ (n & 7))) * 8];
            }
            #pragma unroll
            for (int ti = 0; ti < 4; ++ti)
                #pragma unroll
                for (int tj = 0; tj < 4; ++tj)
                    acc[ti][tj] = __builtin_amdgcn_mfma_f32_16x16x32_bf16(
                        a[ti], b[tj], acc[ti][tj], 0, 0, 0);
        }
    }

    // epilogue: per-lane min over tj, stage in freed staging LDS, then
    // 16-code group minima to gmin.
    float enc[4];
    #pragma unroll
    for (int tj = 0; tj < 4; ++tj)
        enc[tj] = en[nBase + wc * 64 + tj * 16 + l15];

    __syncthreads();
    float* ov = (float*)SBUF;   // [2][128][20] = 20 KB
    #pragma unroll
    for (int ti = 0; ti < 4; ++ti) {
        #pragma unroll
        for (int r = 0; r < 4; ++r) {
            float dmin = enc[0] - 2.0f * acc[ti][0][r];
            #pragma unroll
            for (int tj = 1; tj < 4; ++tj)
                dmin = fminf(dmin, enc[tj] - 2.0f * acc[ti][tj][r]);
            int p = wr * 64 + ti * 16 + quad * 4 + r;
            ov[(wc * 128 + p) * 20 + l15] = dmin;
        }
    }
    __syncthreads();
    #pragma unroll
    for (int it = 0; it < 4; ++it) {
        int id = it * 256 + t;                 // (wcc*128 + p)*4 + sg
        int sg = id & 3;
        const float4 v = *(const float4*)&ov[(id >> 2) * 20 + sg * 4];
        float m = fminf(fminf(v.x, v.y), fminf(v.z, v.w));
        int pp = (id >> 2) & 127;
        int wcc = id >> 9;
        gmin[(size_t)(mBase + pp) * 512 + nb * 8 + wcc * 4 + sg] = m;
    }
}

// ---------------------------------------------------------------------------
// Phase 2 (FUSED with z_q_st + commitment-loss partials): one wave per point.
// Approx global min over 512 group minima; rescore flagged groups exactly in
// fp32 reading emb ROWS cooperatively (coalesced, butterfly-reduced). After
// the final reduce ALL lanes hold the winning (dist,idx); z4 already in
// registers -> straight-through row + loss partial fused.
__global__ __launch_bounds__(256) void k_phase2(
    const float* __restrict__ z, const float* __restrict__ emb,
    const float* __restrict__ A, const float* __restrict__ en,
    const float* __restrict__ gmin,
    int* __restrict__ widx, float* __restrict__ out1,
    int* __restrict__ cnt, float* __restrict__ out0,
    double* __restrict__ part) {
    __shared__ double sred[4];
    int wv = threadIdx.x >> 6;
    int wpt = (blockIdx.x << 2) + wv;  // point id
    int l = threadIdx.x & 63;

    const float* gp = gmin + (size_t)wpt * 512;
    float loc[8];
    #pragma unroll
    for (int i = 0; i < 8; ++i) loc[i] = gp[i * 64 + l];
    float m8 = loc[0];
    #pragma unroll
    for (int i = 1; i < 8; ++i) m8 = fminf(m8, loc[i]);
    #pragma unroll
    for (int off = 1; off < 64; off <<= 1) m8 = fminf(m8, __shfl_xor(m8, off));
    const float thresh = m8 + MARGIN;

    const float4 z4 = *(const float4*)(z + (size_t)wpt * DIM + 4 * l);
    const float Azn = A[wpt];
    unsigned long long best = ~0ull;
    #pragma unroll 1
    for (int i = 0; i < 8; ++i) {
        unsigned long long mask = __ballot(loc[i] <= thresh);
        while (mask) {
            int s = __ffsll((long long)mask) - 1;
            mask &= mask - 1;
            int gid = i * 64 + s;
            int cbase = (gid >> 3) * 128 + ((gid >> 2) & 1) * 64 + (gid & 3) * 4;
            #pragma unroll 4
            for (int k = 0; k < 16; ++k) {
                int c = cbase + (k >> 2) * 16 + (k & 3);
                const float4 ev = *(const float4*)(emb + (size_t)c * DIM + 4 * l);
                float p = fmaf(z4.x, ev.x,
                          fmaf(z4.y, ev.y,
                          fmaf(z4.z, ev.z, z4.w * ev.w)));
                #pragma unroll
                for (int off = 1; off < 64; off <<= 1) p += __shfl_xor(p, off);
                float dist = (Azn - 2.0f * p) + en[c];
                unsigned long long pk =
                    ((unsigned long long)f2ord(dist) << 32) | (unsigned)c;
                best = pk < best ? pk : best;
            }
        }
    }
    const int idx = (int)(unsigned)best;   // all lanes agree post-reduce
    if (l == 0) {
        widx[wpt] = idx;
        out1[wpt] = (float)idx;
        atomicAdd(cnt + idx, 1);
    }

    // ---- fused z_q_st + loss partial (k_zq semantics, verbatim order)
    const float4 ev = *(const float4*)(emb + (size_t)idx * DIM + 4 * l);
    float4 o;
    o.x = ev.x + (z4.x - ev.x);
    o.y = ev.y + (z4.y - ev.y);
    o.z = ev.z + (z4.z - ev.z);
    o.w = ev.w + (z4.w - ev.w);
    *(float4*)(out0 + (size_t)wpt * DIM + 4 * l) = o;

    float t0 = ev.x - z4.x, t1 = ev.y - z4.y, t2 = ev.z - z4.z, t3 = ev.w - z4.w;
    float s0 = t0 * t0, s1 = t1 * t1, s2 = t2 * t2, s3 = t3 * t3;
    double ls = (double)s0 + (double)s1 + (double)s2 + (double)s3;
    #pragma unroll
    for (int off = 32; off > 0; off >>= 1) ls += __shfl_down(ls, off);
    if (l == 0) sred[wv] = ls;
    __syncthreads();
    if (threadIdx.x == 0)
        part[blockIdx.x] = (sred[0] + sred[1]) + (sred[2] + sred[3]);
}

// ---------------------------------------------------------------------------
// single block: exclusive prefix of cnt -> offs (+cursor copy);
// out4 = ecs*0.99 + cnt*0.01; n = sum(out4); smoothed -> s_out.
// FUSED: loss partial sum -> out2 (identical summation order to old k_loss).
__global__ __launch_bounds__(256) void k_scan(const int* __restrict__ cnt,
                                              const float* __restrict__ ecs,
                                              int* __restrict__ offs,
                                              int* __restrict__ cursor,
                                              float* __restrict__ out4,
                                              float* __restrict__ s_out,
                                              const double* __restrict__ part,
                                              float* __restrict__ out2) {
    __shared__ int ps[256];
    __shared__ double rd[256];
    __shared__ float nsh;
    int t = threadIdx.x;
    int base = t * 32;
    int loc[32];
    int s = 0;
    double nl = 0.0;
    #pragma unroll
    for (int i = 0; i < 32; ++i) {
        int c = cnt[base + i];
        loc[i] = c;
        s += c;
        float f = ecs[base + i] * DECAYF + (float)c * ONE_MINUS_DECAYF;
        out4[base + i] = f;
        nl += (double)f;
    }
    ps[t] = s;
    rd[t] = nl;
    __syncthreads();
    for (int off = 1; off < 256; off <<= 1) {
        int v = (t >= off) ? ps[t - off] : 0;
        __syncthreads();
        ps[t] += v;
        __syncthreads();
    }
    for (int off = 128; off > 0; off >>= 1) {
        if (t < off) rd[t] += rd[t + off];
        __syncthreads();
    }
    if (t == 0) nsh = (float)rd[0];
    __syncthreads();
    int run = (t == 0) ? 0 : ps[t - 1];
    #pragma unroll
    for (int i = 0; i < 32; ++i) {
        offs[base + i] = run;
        cursor[base + i] = run;
        run += loc[i];
    }
    float n = nsh;
    for (int k = t; k < NCODES; k += 256)
        s_out[k] = (out4[k] + EPSF) / (n + KEPSF) * n;

    // ---- fused loss reduction (old k_loss, bit-identical order)
    __syncthreads();
    double lsum = 0.0;
    for (int i = t; i < NPTS / 4; i += 256) lsum += part[i];
    rd[t] = lsum;
    __syncthreads();
    for (int off = 128; off > 0; off >>= 1) {
        if (t < off) rd[t] += rd[t + off];
        __syncthreads();
    }
    if (t == 0)
        out2[0] = 0.25f * (float)(rd[0] / (double)((size_t)NPTS * DIM));
}

// ---------------------------------------------------------------------------
__global__ __launch_bounds__(256) void k_place(const int* __restrict__ widx,
                                               int* __restrict__ cursor,
                                               int* __restrict__ plist) {
    int p = blockIdx.x * 256 + threadIdx.x;
    int idx = widx[p];
    int slot = atomicAdd(&cursor[idx], 1);
    plist[slot] = p;
}

// ---------------------------------------------------------------------------
// one wave per code: out5 = 0.99*eem + 0.01*sum(z[points of code]);
// FUSED: out3 = out5 / smoothed[c]  (old k_final).
__global__ __launch_bounds__(256) void k_dw(const float* __restrict__ z,
                                            const float* __restrict__ eem,
                                            const int* __restrict__ offs,
                                            const int* __restrict__ cnt,
                                            const int* __restrict__ plist,
                                            const float* __restrict__ s,
                                            float* __restrict__ out5,
                                            float* __restrict__ out3) {
    int c = blockIdx.x * 4 + (threadIdx.x >> 6);
    int lane = threadIdx.x & 63;
    int beg = offs[c], num = cnt[c];
    float4 acc = make_float4(0.f, 0.f, 0.f, 0.f);
    for (int j = 0; j < num; ++j) {
        int p = plist[beg + j];
        const float4 v = *(const float4*)(z + (size_t)p * DIM + 4 * lane);
        acc.x += v.x; acc.y += v.y; acc.z += v.z; acc.w += v.w;
    }
    const float4 e = *(const float4*)(eem + (size_t)c * DIM + 4 * lane);
    float4 o;
    o.x = e.x * DECAYF + acc.x * ONE_MINUS_DECAYF;
    o.y = e.y * DECAYF + acc.y * ONE_MINUS_DECAYF;
    o.z = e.z * DECAYF + acc.z * ONE_MINUS_DECAYF;
    o.w = e.w * DECAYF + acc.w * ONE_MINUS_DECAYF;
    *(float4*)(out5 + (size_t)c * DIM + 4 * lane) = o;
    const float sc = s[c];
    float4 o3;
    o3.x = o.x / sc; o3.y = o.y / sc; o3.z = o.z / sc; o3.w = o.w / sc;
    *(float4*)(out3 + (size_t)c * DIM + 4 * lane) = o3;
}

// ---------------------------------------------------------------------------
extern "C" void kernel_launch(void* const* d_in, const int* in_sizes, int n_in,
                              void* d_out, int out_size, void* d_ws, size_t ws_size,
                              hipStream_t stream) {
    const float* z   = (const float*)d_in[0];
    const float* emb = (const float*)d_in[1];
    const float* ecs = (const float*)d_in[2];
    const float* eem = (const float*)d_in[3];

    float* out = (float*)d_out;
    float* out0 = out;                   // z_q_st         [8388608]
    float* out1 = out + 8388608;         // indices        [32768]
    float* out2 = out + 8421376;         // vq_loss        [1]
    float* out3 = out + 8421377;         // new_embedding  [2097152]
    float* out4 = out + 10518529;        // new_ema_cs     [8192]
    float* out5 = out + 10526721;        // new_ema_emb    [2097152]

    char* ws = (char*)d_ws;
    double* wPart = (double*)(ws + WS_PART);
    float*  wA    = (float*)(ws + WS_A);
    float*  wEn   = (float*)(ws + WS_EN);
    int*    wCnt  = (int*)(ws + WS_CNT);
    float*  wS    = (float*)(ws + WS_S);
    int*    wIdx  = (int*)(ws + WS_IDX);
    int*    wOffs = (int*)(ws + WS_OFFS);
    int*    wCur  = (int*)(ws + WS_CUR);
    int*    wPl   = (int*)(ws + WS_PLIST);
    float*  wGmin = (float*)(ws + WS_GMIN);
    unsigned short* wAh = (unsigned short*)(ws + WS_AH);
    unsigned short* wBh = (unsigned short*)(ws + WS_BH);

    hipLaunchKernelGGL(k_prep, dim3(NPTS / 4 + NCODES / 4), dim3(256), 0, stream,
                       z, emb, wA, wAh, wEn, wBh, wCnt);
    // GEMM split into 4 quarter-grids (diagnostic: drops the top-5 visibility
    // threshold from ~152us to ~40us so non-GEMM kernels surface).
    hipLaunchKernelGGL(k_gemm_argmin, dim3(4096), dim3(256), 0, stream,
                       wAh, wBh, wEn, wGmin, 0);
    hipLaunchKernelGGL(k_gemm_argmin, dim3(4096), dim3(256), 0, stream,
                       wAh, wBh, wEn, wGmin, 64);
    hipLaunchKernelGGL(k_gemm_argmin, dim3(4096), dim3(256), 0, stream,
                       wAh, wBh, wEn, wGmin, 128);
    hipLaunchKernelGGL(k_gemm_argmin, dim3(4096), dim3(256), 0, stream,
                       wAh, wBh, wEn, wGmin, 192);
    hipLaunchKernelGGL(k_phase2, dim3(NPTS / 4), dim3(256), 0, stream,
                       z, emb, wA, wEn, wGmin, wIdx, out1, wCnt, out0, wPart);
    hipLaunchKernelGGL(k_scan, dim3(1), dim3(256), 0, stream,
                       wCnt, ecs, wOffs, wCur, out4, wS, wPart, out2);
    hipLaunchKernelGGL(k_place, dim3(NPTS / 256), dim3(256), 0, stream, wIdx, wCur, wPl);
    hipLaunchKernelGGL(k_dw, dim3(NCODES / 4), dim3(256), 0, stream,
                       z, eem, wOffs, wCnt, wPl, wS, out5, out3);
}

// Round 9
// 354.472 us; speedup vs baseline: 1.0250x; 1.0250x over previous
//
#include <hip/hip_runtime.h>

#define NPTS   32768
#define NCODES 8192
#define DIM    256

#define DECAYF 0.99f
#define ONE_MINUS_DECAYF ((float)(1.0 - 0.99))
#define EPSF   1e-5f
#define KEPSF  ((float)(8192.0 * 1e-5))
#define MARGIN 0.05f

// workspace byte offsets
#define WS_PART  0                                     // fp64 [8192] loss partials
#define WS_A     (WS_PART + NPTS / 4 * 8)              // fp32 [NPTS]
#define WS_EN    (WS_A + NPTS * 4)                     // fp32 [NCODES]
#define WS_CNT   (WS_EN + NCODES * 4)                  // int  [NCODES]
#define WS_S     (WS_CNT + NCODES * 4)                 // fp32 [NCODES] smoothed
#define WS_IDX   (WS_S + NCODES * 4)                   // int  [NPTS]
#define WS_OFFS  (WS_IDX + NPTS * 4)                   // int  [NCODES]
#define WS_CUR   (WS_OFFS + NCODES * 4)                // int  [NCODES]
#define WS_PLIST (WS_CUR + NCODES * 4)                 // int  [NPTS]
#define WS_EMBT  (WS_PLIST + NPTS * 4)                 // (unused, kept for layout)
#define WS_GMIN  (WS_EMBT + (size_t)DIM * NCODES * 4)  // fp32 [NPTS][512]     64 MB
#define WS_AH    (WS_GMIN + (size_t)NPTS * 512 * 4)    // bf16 [NPTS][256]     16 MB
#define WS_BH    (WS_AH + (size_t)NPTS * DIM * 2)      // bf16 [NCODES][256]    4 MB

typedef __attribute__((ext_vector_type(8))) short short8;
typedef __attribute__((ext_vector_type(4))) float f32x4;

__device__ inline void gl_lds16(const void* g, void* l) {
    __builtin_amdgcn_global_load_lds(
        (const __attribute__((address_space(1))) void*)g,
        (__attribute__((address_space(3))) void*)l, 16, 0, 0);
}

__device__ inline unsigned short f2bf(float f) {  // RNE float->bf16
    unsigned u = __float_as_uint(f);
    return (unsigned short)((u + 0x7FFFu + ((u >> 16) & 1u)) >> 16);
}
__device__ inline unsigned f2ord(float f) {       // monotone float->uint
    unsigned u = __float_as_uint(f);
    return (u & 0x80000000u) ? ~u : (u | 0x80000000u);
}

// ---------------------------------------------------------------------------
// Fused prep: row squared-norm + fp32->bf16-hi copy for BOTH z and emb, plus
// cnt zeroing (one launch replaces 3). Block-uniform branch on blockIdx.
__device__ __forceinline__ void rownorm_split_row(
    const float* __restrict__ x, float* __restrict__ outn,
    unsigned short* __restrict__ dst, int w, int lane) {
    const float4 v = *(const float4*)(x + (size_t)w * DIM + 4 * lane);
    ushort4 h;
    h.x = f2bf(v.x); h.y = f2bf(v.y); h.z = f2bf(v.z); h.w = f2bf(v.w);
    *(ushort4*)(dst + (size_t)w * DIM + 4 * lane) = h;
    float q0 = v.x * v.x, q1 = v.y * v.y, q2 = v.z * v.z, q3 = v.w * v.w;
    double s = (double)q0 + (double)q1 + (double)q2 + (double)q3;
    #pragma unroll
    for (int off = 32; off > 0; off >>= 1) s += __shfl_down(s, off);
    if (lane == 0) outn[w] = (float)s;
}

__global__ __launch_bounds__(256) void k_prep(
    const float* __restrict__ z, const float* __restrict__ emb,
    float* __restrict__ wA, unsigned short* __restrict__ wAh,
    float* __restrict__ wEn, unsigned short* __restrict__ wBh,
    int* __restrict__ cnt) {
    const int b = blockIdx.x;
    const int lane = threadIdx.x & 63;
    if (b < NPTS / 4) {
        int w = (b * 256 + (int)threadIdx.x) >> 6;
        rownorm_split_row(z, wA, wAh, w, lane);
    } else {
        int b2 = b - NPTS / 4;
        if (b2 < 32) cnt[b2 * 256 + threadIdx.x] = 0;
        int w = (b2 * 256 + (int)threadIdx.x) >> 6;
        rownorm_split_row(emb, wEn, wBh, w, lane);
    }
}

// ---------------------------------------------------------------------------
// Phase 1: bf16-hi MFMA GEMM (M=32768, N=8192, K=256), fused epilogue writes
// per-16-code-group approx min distance (fp32) to gmin[NPTS][512].
// (128x128 tile, 4 waves, 32KB LDS -- measured ~152us/~900TF, at this
// structure's ceiling; deeper pipelines measured WORSE on this shape.
// Single launch: 4-way diagnostic split measured ~equal but costs 3 gaps.)
__global__ __launch_bounds__(256) void k_gemm_argmin(
    const unsigned short* __restrict__ Ah,    // [NPTS][256] bf16 bits
    const unsigned short* __restrict__ Bh,    // [NCODES][256] bf16 bits
    const float* __restrict__ en,
    float* __restrict__ gmin) {               // [NPTS][512]
    __shared__ __align__(16) unsigned short SBUF[16384];  // 32 KB: A | B

    const int t = threadIdx.x;
    const int w = t >> 6, l = t & 63;
    const int quad = l >> 4, l15 = l & 15;
    const int wr = w >> 1, wc = w & 1;
    const int mb = blockIdx.x >> 6, nb = blockIdx.x & 63;
    const int mBase = mb * 128, nBase = nb * 128;

    // staging swizzle: slot s covers (row=s>>3, x=s&7, kchunk = x ^ (row&7))
    const int xr = (t & 7) ^ ((t >> 3) & 7);
    const int rrow = t >> 3;
    const unsigned short* ag[4];
    const unsigned short* bg[4];
    #pragma unroll
    for (int i = 0; i < 4; ++i) {
        ag[i] = Ah + (size_t)(mBase + i * 32 + rrow) * DIM + xr * 8;
        bg[i] = Bh + (size_t)(nBase + i * 32 + rrow) * DIM + xr * 8;
    }

    f32x4 acc[4][4];
    #pragma unroll
    for (int i = 0; i < 4; ++i)
        #pragma unroll
        for (int j = 0; j < 4; ++j)
            acc[i][j] = (f32x4){0.f, 0.f, 0.f, 0.f};

    for (int kt = 0; kt < 4; ++kt) {
        __syncthreads();
        #pragma unroll
        for (int i = 0; i < 4; ++i) {
            gl_lds16(ag[i], &SBUF[(i * 256 + w * 64) * 8]);
            gl_lds16(bg[i], &SBUF[8192 + (i * 256 + w * 64) * 8]);
            ag[i] += 64; bg[i] += 64;
        }
        __syncthreads();
        #pragma unroll
        for (int kk = 0; kk < 2; ++kk) {
            const int kc = kk * 4 + quad;
            short8 a[4], b[4];
            #pragma unroll
            for (int ti = 0; ti < 4; ++ti) {
                int m = wr * 64 + ti * 16 + l15;
                a[ti] = *(const short8*)&SBUF[(m * 8 + (kc ^ (m & 7))) * 8];
                int n = wc * 64 + ti * 16 + l15;
                b[ti] = *(const short8*)&SBUF[8192 + (n * 8 + (kc ^ (n & 7))) * 8];
            }
            #pragma unroll
            for (int ti = 0; ti < 4; ++ti)
                #pragma unroll
                for (int tj = 0; tj < 4; ++tj)
                    acc[ti][tj] = __builtin_amdgcn_mfma_f32_16x16x32_bf16(
                        a[ti], b[tj], acc[ti][tj], 0, 0, 0);
        }
    }

    // epilogue: per-lane min over tj, stage in freed staging LDS, then
    // 16-code group minima to gmin.
    float enc[4];
    #pragma unroll
    for (int tj = 0; tj < 4; ++tj)
        enc[tj] = en[nBase + wc * 64 + tj * 16 + l15];

    __syncthreads();
    float* ov = (float*)SBUF;   // [2][128][20] = 20 KB
    #pragma unroll
    for (int ti = 0; ti < 4; ++ti) {
        #pragma unroll
        for (int r = 0; r < 4; ++r) {
            float dmin = enc[0] - 2.0f * acc[ti][0][r];
            #pragma unroll
            for (int tj = 1; tj < 4; ++tj)
                dmin = fminf(dmin, enc[tj] - 2.0f * acc[ti][tj][r]);
            int p = wr * 64 + ti * 16 + quad * 4 + r;
            ov[(wc * 128 + p) * 20 + l15] = dmin;
        }
    }
    __syncthreads();
    #pragma unroll
    for (int it = 0; it < 4; ++it) {
        int id = it * 256 + t;                 // (wcc*128 + p)*4 + sg
        int sg = id & 3;
        const float4 v = *(const float4*)&ov[(id >> 2) * 20 + sg * 4];
        float m = fminf(fminf(v.x, v.y), fminf(v.z, v.w));
        int pp = (id >> 2) & 127;
        int wcc = id >> 9;
        gmin[(size_t)(mBase + pp) * 512 + nb * 8 + wcc * 4 + sg] = m;
    }
}

// ---------------------------------------------------------------------------
// Phase 2 (FUSED with z_q_st + commitment-loss partials): one wave per point.
// Approx global min over 512 group minima; rescore flagged groups exactly in
// fp32 reading emb ROWS cooperatively. LATENCY FIX (measured 78us, 0 MFMA,
// VALUBusy 38%, HBM 43% -- latency-bound): batch 8 row loads in flight per
// half-group (ev[8], fully unrolled -> static indexing) instead of unroll-4;
// en via one float4 per half. Dot/reduce/pack order verbatim -> selection
// bit-identical.
__global__ __launch_bounds__(256) void k_phase2(
    const float* __restrict__ z, const float* __restrict__ emb,
    const float* __restrict__ A, const float* __restrict__ en,
    const float* __restrict__ gmin,
    int* __restrict__ widx, float* __restrict__ out1,
    int* __restrict__ cnt, float* __restrict__ out0,
    double* __restrict__ part) {
    __shared__ double sred[4];
    int wv = threadIdx.x >> 6;
    int wpt = (blockIdx.x << 2) + wv;  // point id
    int l = threadIdx.x & 63;

    const float* gp = gmin + (size_t)wpt * 512;
    float loc[8];
    #pragma unroll
    for (int i = 0; i < 8; ++i) loc[i] = gp[i * 64 + l];
    float m8 = loc[0];
    #pragma unroll
    for (int i = 1; i < 8; ++i) m8 = fminf(m8, loc[i]);
    #pragma unroll
    for (int off = 1; off < 64; off <<= 1) m8 = fminf(m8, __shfl_xor(m8, off));
    const float thresh = m8 + MARGIN;

    const float4 z4 = *(const float4*)(z + (size_t)wpt * DIM + 4 * l);
    const float Azn = A[wpt];
    unsigned long long best = ~0ull;
    #pragma unroll 1
    for (int i = 0; i < 8; ++i) {
        unsigned long long mask = __ballot(loc[i] <= thresh);
        while (mask) {
            int s = __ffsll((long long)mask) - 1;
            mask &= mask - 1;
            int gid = i * 64 + s;
            int cbase = (gid >> 3) * 128 + ((gid >> 2) & 1) * 64 + (gid & 3) * 4;
            #pragma unroll 1
            for (int kh = 0; kh < 2; ++kh) {
                // codes k = kh*8 + k8; c = cbase + (k>>2)*16 + (k&3)
                const int cb2 = cbase + kh * 32;
                float4 ev[8];
                #pragma unroll
                for (int k8 = 0; k8 < 8; ++k8) {
                    const int c = cb2 + (k8 >> 2) * 16 + (k8 & 3);
                    ev[k8] = *(const float4*)(emb + (size_t)c * DIM + 4 * l);
                }
                const float4 enA = *(const float4*)&en[cb2];
                const float4 enB = *(const float4*)&en[cb2 + 16];
                #pragma unroll
                for (int k8 = 0; k8 < 8; ++k8) {
                    const int c = cb2 + (k8 >> 2) * 16 + (k8 & 3);
                    float p = fmaf(z4.x, ev[k8].x,
                              fmaf(z4.y, ev[k8].y,
                              fmaf(z4.z, ev[k8].z, z4.w * ev[k8].w)));
                    #pragma unroll
                    for (int off = 1; off < 64; off <<= 1) p += __shfl_xor(p, off);
                    const float4 en4 = (k8 < 4) ? enA : enB;
                    const int k2 = k8 & 3;
                    float enk = (k2 == 0) ? en4.x : (k2 == 1) ? en4.y
                               : (k2 == 2) ? en4.z : en4.w;
                    float dist = (Azn - 2.0f * p) + enk;
                    unsigned long long pk =
                        ((unsigned long long)f2ord(dist) << 32) | (unsigned)c;
                    best = pk < best ? pk : best;
                }
            }
        }
    }
    const int idx = (int)(unsigned)best;   // all lanes agree post-reduce
    if (l == 0) {
        widx[wpt] = idx;
        out1[wpt] = (float)idx;
        atomicAdd(cnt + idx, 1);
    }

    // ---- fused z_q_st + loss partial (k_zq semantics, verbatim order)
    const float4 ev = *(const float4*)(emb + (size_t)idx * DIM + 4 * l);
    float4 o;
    o.x = ev.x + (z4.x - ev.x);
    o.y = ev.y + (z4.y - ev.y);
    o.z = ev.z + (z4.z - ev.z);
    o.w = ev.w + (z4.w - ev.w);
    *(float4*)(out0 + (size_t)wpt * DIM + 4 * l) = o;

    float t0 = ev.x - z4.x, t1 = ev.y - z4.y, t2 = ev.z - z4.z, t3 = ev.w - z4.w;
    float s0 = t0 * t0, s1 = t1 * t1, s2 = t2 * t2, s3 = t3 * t3;
    double ls = (double)s0 + (double)s1 + (double)s2 + (double)s3;
    #pragma unroll
    for (int off = 32; off > 0; off >>= 1) ls += __shfl_down(ls, off);
    if (l == 0) sred[wv] = ls;
    __syncthreads();
    if (threadIdx.x == 0)
        part[blockIdx.x] = (sred[0] + sred[1]) + (sred[2] + sred[3]);
}

// ---------------------------------------------------------------------------
// single block: exclusive prefix of cnt -> offs (+cursor copy);
// out4 = ecs*0.99 + cnt*0.01; n = sum(out4); smoothed -> s_out.
// FUSED: loss partial sum -> out2 (identical summation order to old k_loss).
__global__ __launch_bounds__(256) void k_scan(const int* __restrict__ cnt,
                                              const float* __restrict__ ecs,
                                              int* __restrict__ offs,
                                              int* __restrict__ cursor,
                                              float* __restrict__ out4,
                                              float* __restrict__ s_out,
                                              const double* __restrict__ part,
                                              float* __restrict__ out2) {
    __shared__ int ps[256];
    __shared__ double rd[256];
    __shared__ float nsh;
    int t = threadIdx.x;
    int base = t * 32;
    int loc[32];
    int s = 0;
    double nl = 0.0;
    #pragma unroll
    for (int i = 0; i < 32; ++i) {
        int c = cnt[base + i];
        loc[i] = c;
        s += c;
        float f = ecs[base + i] * DECAYF + (float)c * ONE_MINUS_DECAYF;
        out4[base + i] = f;
        nl += (double)f;
    }
    ps[t] = s;
    rd[t] = nl;
    __syncthreads();
    for (int off = 1; off < 256; off <<= 1) {
        int v = (t >= off) ? ps[t - off] : 0;
        __syncthreads();
        ps[t] += v;
        __syncthreads();
    }
    for (int off = 128; off > 0; off >>= 1) {
        if (t < off) rd[t] += rd[t + off];
        __syncthreads();
    }
    if (t == 0) nsh = (float)rd[0];
    __syncthreads();
    int run = (t == 0) ? 0 : ps[t - 1];
    #pragma unroll
    for (int i = 0; i < 32; ++i) {
        offs[base + i] = run;
        cursor[base + i] = run;
        run += loc[i];
    }
    float n = nsh;
    for (int k = t; k < NCODES; k += 256)
        s_out[k] = (out4[k] + EPSF) / (n + KEPSF) * n;

    // ---- fused loss reduction (old k_loss, bit-identical order)
    __syncthreads();
    double lsum = 0.0;
    for (int i = t; i < NPTS / 4; i += 256) lsum += part[i];
    rd[t] = lsum;
    __syncthreads();
    for (int off = 128; off > 0; off >>= 1) {
        if (t < off) rd[t] += rd[t + off];
        __syncthreads();
    }
    if (t == 0)
        out2[0] = 0.25f * (float)(rd[0] / (double)((size_t)NPTS * DIM));
}

// ---------------------------------------------------------------------------
__global__ __launch_bounds__(256) void k_place(const int* __restrict__ widx,
                                               int* __restrict__ cursor,
                                               int* __restrict__ plist) {
    int p = blockIdx.x * 256 + threadIdx.x;
    int idx = widx[p];
    int slot = atomicAdd(&cursor[idx], 1);
    plist[slot] = p;
}

// ---------------------------------------------------------------------------
// one wave per code: out5 = 0.99*eem + 0.01*sum(z[points of code]);
// FUSED: out3 = out5 / smoothed[c]  (old k_final).
__global__ __launch_bounds__(256) void k_dw(const float* __restrict__ z,
                                            const float* __restrict__ eem,
                                            const int* __restrict__ offs,
                                            const int* __restrict__ cnt,
                                            const int* __restrict__ plist,
                                            const float* __restrict__ s,
                                            float* __restrict__ out5,
                                            float* __restrict__ out3) {
    int c = blockIdx.x * 4 + (threadIdx.x >> 6);
    int lane = threadIdx.x & 63;
    int beg = offs[c], num = cnt[c];
    float4 acc = make_float4(0.f, 0.f, 0.f, 0.f);
    for (int j = 0; j < num; ++j) {
        int p = plist[beg + j];
        const float4 v = *(const float4*)(z + (size_t)p * DIM + 4 * lane);
        acc.x += v.x; acc.y += v.y; acc.z += v.z; acc.w += v.w;
    }
    const float4 e = *(const float4*)(eem + (size_t)c * DIM + 4 * lane);
    float4 o;
    o.x = e.x * DECAYF + acc.x * ONE_MINUS_DECAYF;
    o.y = e.y * DECAYF + acc.y * ONE_MINUS_DECAYF;
    o.z = e.z * DECAYF + acc.z * ONE_MINUS_DECAYF;
    o.w = e.w * DECAYF + acc.w * ONE_MINUS_DECAYF;
    *(float4*)(out5 + (size_t)c * DIM + 4 * lane) = o;
    const float sc = s[c];
    float4 o3;
    o3.x = o.x / sc; o3.y = o.y / sc; o3.z = o.z / sc; o3.w = o.w / sc;
    *(float4*)(out3 + (size_t)c * DIM + 4 * lane) = o3;
}

// ---------------------------------------------------------------------------
extern "C" void kernel_launch(void* const* d_in, const int* in_sizes, int n_in,
                              void* d_out, int out_size, void* d_ws, size_t ws_size,
                              hipStream_t stream) {
    const float* z   = (const float*)d_in[0];
    const float* emb = (const float*)d_in[1];
    const float* ecs = (const float*)d_in[2];
    const float* eem = (const float*)d_in[3];

    float* out = (float*)d_out;
    float* out0 = out;                   // z_q_st         [8388608]
    float* out1 = out + 8388608;         // indices        [32768]
    float* out2 = out + 8421376;         // vq_loss        [1]
    float* out3 = out + 8421377;         // new_embedding  [2097152]
    float* out4 = out + 10518529;        // new_ema_cs     [8192]
    float* out5 = out + 10526721;        // new_ema_emb    [2097152]

    char* ws = (char*)d_ws;
    double* wPart = (double*)(ws + WS_PART);
    float*  wA    = (float*)(ws + WS_A);
    float*  wEn   = (float*)(ws + WS_EN);
    int*    wCnt  = (int*)(ws + WS_CNT);
    float*  wS    = (float*)(ws + WS_S);
    int*    wIdx  = (int*)(ws + WS_IDX);
    int*    wOffs = (int*)(ws + WS_OFFS);
    int*    wCur  = (int*)(ws + WS_CUR);
    int*    wPl   = (int*)(ws + WS_PLIST);
    float*  wGmin = (float*)(ws + WS_GMIN);
    unsigned short* wAh = (unsigned short*)(ws + WS_AH);
    unsigned short* wBh = (unsigned short*)(ws + WS_BH);

    hipLaunchKernelGGL(k_prep, dim3(NPTS / 4 + NCODES / 4), dim3(256), 0, stream,
                       z, emb, wA, wAh, wEn, wBh, wCnt);
    hipLaunchKernelGGL(k_gemm_argmin, dim3((NPTS / 128) * (NCODES / 128)), dim3(256), 0, stream,
                       wAh, wBh, wEn, wGmin);
    hipLaunchKernelGGL(k_phase2, dim3(NPTS / 4), dim3(256), 0, stream,
                       z, emb, wA, wEn, wGmin, wIdx, out1, wCnt, out0, wPart);
    hipLaunchKernelGGL(k_scan, dim3(1), dim3(256), 0, stream,
                       wCnt, ecs, wOffs, wCur, out4, wS, wPart, out2);
    hipLaunchKernelGGL(k_place, dim3(NPTS / 256), dim3(256), 0, stream, wIdx, wCur, wPl);
    hipLaunchKernelGGL(k_dw, dim3(NCODES / 4), dim3(256), 0, stream,
                       z, eem, wOffs, wCnt, wPl, wS, out5, out3);
}